// Round 1
// baseline (1116.891 us; speedup 1.0000x reference)
//
#include <hip/hip_runtime.h>
#include <math.h>

// ---------------------------------------------------------------------------
// GAT 4-layer forward. Structure:
//   per call: build dst-CSR (hist -> scan -> scatter) from edge_index,
//   then per layer: fp32 tiled GEMM (h = in @ W), alpha kernel (as/ad per
//   node/head), aggregation kernel (online softmax over incoming edges,
//   register-accumulated feature row, fused bias + relu).
// ---------------------------------------------------------------------------

static __global__ void zero_int(int* __restrict__ p, int n) {
    int i = blockIdx.x * blockDim.x + threadIdx.x;
    if (i < n) p[i] = 0;
}

// histogram of dst (self-loops appended: edge id e0+k has src=dst=k)
static __global__ void hist_kernel(const int* __restrict__ ei, int e0, int n_nodes,
                                   int* __restrict__ counts) {
    int e = blockIdx.x * blockDim.x + threadIdx.x;
    int et = e0 + n_nodes;
    if (e >= et) return;
    int d = (e < e0) ? ei[e0 + e] : (e - e0);
    atomicAdd(&counts[d], 1);
}

// single-block exclusive scan: row_ptr[0]=0, row_ptr[i+1]=sum(counts[0..i])
static __global__ void scan_kernel(const int* __restrict__ counts,
                                   int* __restrict__ row_ptr, int n) {
    __shared__ int sdata[1024];
    __shared__ int carry;
    if (threadIdx.x == 0) carry = 0;
    __syncthreads();
    for (int base = 0; base < n; base += 1024) {
        int i = base + (int)threadIdx.x;
        int v = (i < n) ? counts[i] : 0;
        sdata[threadIdx.x] = v;
        __syncthreads();
        for (int off = 1; off < 1024; off <<= 1) {
            int t = 0;
            if ((int)threadIdx.x >= off) t = sdata[threadIdx.x - off];
            __syncthreads();
            if ((int)threadIdx.x >= off) sdata[threadIdx.x] += t;
            __syncthreads();
        }
        int inc = sdata[threadIdx.x] + carry;   // inclusive prefix + carry
        if (i < n) row_ptr[i + 1] = inc;
        __syncthreads();
        if (threadIdx.x == 1023) carry = inc;
        __syncthreads();
    }
    if (threadIdx.x == 0) row_ptr[0] = 0;
}

static __global__ void scatter_kernel(const int* __restrict__ ei, int e0, int n_nodes,
                                      const int* __restrict__ row_ptr,
                                      int* __restrict__ cursor,
                                      int* __restrict__ src_sorted) {
    int e = blockIdx.x * blockDim.x + threadIdx.x;
    int et = e0 + n_nodes;
    if (e >= et) return;
    int s, d;
    if (e < e0) { s = ei[e]; d = ei[e0 + e]; } else { s = e - e0; d = s; }
    int pos = atomicAdd(&cursor[d], 1);
    src_sorted[row_ptr[d] + pos] = s;
}

// ---------------------------------------------------------------------------
// fp32 tiled GEMM: C[M,N] = A[M,K] @ B[K,N]. N%64==0, K%16==0, M guarded.
// 64x64 tile, 256 threads, 4x4 microtile, LDS-staged with A transposed.
// ---------------------------------------------------------------------------
#define TM 64
#define TN 64
#define TK 16

__launch_bounds__(256)
static __global__ void gemm_kernel(const float* __restrict__ A, const float* __restrict__ B,
                                   float* __restrict__ C, int M, int K, int N) {
    __shared__ float As[TK][TM + 4];   // As[k][m]
    __shared__ float Bs[TK][TN + 4];   // Bs[k][n]
    int t = threadIdx.x;
    int m0 = blockIdx.y * TM;
    int n0 = blockIdx.x * TN;
    int tx = t & 15, ty = t >> 4;

    int ar = t >> 2;            // 0..63 (tile row)
    int ak = (t & 3) * 4;       // 0,4,8,12
    int br = t >> 4;            // 0..15 (tile k)
    int bc = (t & 15) * 4;      // 0..60

    bool arow_ok = (m0 + ar) < M;
    const float* Aptr = A + (size_t)(m0 + ar) * K + ak;
    const float* Bptr = B + (size_t)br * N + n0 + bc;

    float acc[4][4];
#pragma unroll
    for (int i = 0; i < 4; i++)
#pragma unroll
        for (int j = 0; j < 4; j++) acc[i][j] = 0.f;

    for (int k0 = 0; k0 < K; k0 += TK) {
        float4 av = arow_ok ? *(const float4*)(Aptr + k0)
                            : make_float4(0.f, 0.f, 0.f, 0.f);
        float4 bv = *(const float4*)(Bptr + (size_t)k0 * N);
        __syncthreads();
        As[ak + 0][ar] = av.x;
        As[ak + 1][ar] = av.y;
        As[ak + 2][ar] = av.z;
        As[ak + 3][ar] = av.w;
        *(float4*)&Bs[br][bc] = bv;
        __syncthreads();
#pragma unroll
        for (int k = 0; k < TK; k++) {
            float4 a = *(const float4*)&As[k][ty * 4];
            float4 b = *(const float4*)&Bs[k][tx * 4];
            acc[0][0] += a.x * b.x; acc[0][1] += a.x * b.y; acc[0][2] += a.x * b.z; acc[0][3] += a.x * b.w;
            acc[1][0] += a.y * b.x; acc[1][1] += a.y * b.y; acc[1][2] += a.y * b.z; acc[1][3] += a.y * b.w;
            acc[2][0] += a.z * b.x; acc[2][1] += a.z * b.y; acc[2][2] += a.z * b.z; acc[2][3] += a.z * b.w;
            acc[3][0] += a.w * b.x; acc[3][1] += a.w * b.y; acc[3][2] += a.w * b.z; acc[3][3] += a.w * b.w;
        }
    }
#pragma unroll
    for (int i = 0; i < 4; i++) {
        int row = m0 + ty * 4 + i;
        if (row < M) {
            float4 v = make_float4(acc[i][0], acc[i][1], acc[i][2], acc[i][3]);
            *(float4*)&C[(size_t)row * N + n0 + tx * 4] = v;
        }
    }
}

// ---------------------------------------------------------------------------
// alpha kernel: as[n,h] = sum_c h[n,h,c]*a_src[h,c]; same for ad. One wave/node.
// ---------------------------------------------------------------------------
template <int H, int C>
__launch_bounds__(256)
static __global__ void alpha_kernel(const float* __restrict__ h,
                                    const float* __restrict__ a_src,
                                    const float* __restrict__ a_dst,
                                    float* __restrict__ as_out,
                                    float* __restrict__ ad_out, int n_nodes) {
    constexpr int R = H * C / 64;   // elems per lane
    constexpr int G = 64 / H;       // lanes per head
    int wave = threadIdx.x >> 6;
    int lane = threadIdx.x & 63;
    int n = blockIdx.x * 4 + wave;
    if (n >= n_nodes) return;
    const float* row = h + (size_t)n * (H * C) + lane * R;
    float ssrc = 0.f, sdst = 0.f;
#pragma unroll
    for (int r = 0; r < R; r++) {
        float v = row[r];
        int f = lane * R + r;
        ssrc += v * a_src[f];
        sdst += v * a_dst[f];
    }
#pragma unroll
    for (int off = G / 2; off > 0; off >>= 1) {
        ssrc += __shfl_down(ssrc, off);
        sdst += __shfl_down(sdst, off);
    }
    if ((lane & (G - 1)) == 0) {
        int head = lane / G;
        as_out[(size_t)n * H + head] = ssrc;
        ad_out[(size_t)n * H + head] = sdst;
    }
}

// ---------------------------------------------------------------------------
// aggregation: one wave per node. Online softmax over incoming edges (CSR),
// accumulate weighted src feature rows in registers. Fused bias + relu.
// ---------------------------------------------------------------------------
template <int H, int C>
__launch_bounds__(256)
static __global__ void agg_kernel(const float* __restrict__ h,
                                  const float* __restrict__ as_arr,
                                  const float* __restrict__ ad_arr,
                                  const int* __restrict__ row_ptr,
                                  const int* __restrict__ src_sorted,
                                  const float* __restrict__ bias,
                                  float* __restrict__ out, int n_nodes) {
    constexpr int R = H * C / 64;   // elems per lane
    constexpr int G = 64 / H;       // lanes per head
    int wave = threadIdx.x >> 6;
    int lane = threadIdx.x & 63;
    int n = blockIdx.x * 4 + wave;
    if (n >= n_nodes) return;
    int myh = lane / G;
    float ad_n = ad_arr[(size_t)n * H + myh];
    int beg = row_ptr[n], end = row_ptr[n + 1];

    float m = -INFINITY, l = 0.f;
    float acc[R];
#pragma unroll
    for (int r = 0; r < R; r++) acc[r] = 0.f;

    for (int j = beg; j < end; j++) {
        int s = src_sorted[j];
        float e = as_arr[(size_t)s * H + myh] + ad_n;
        e = (e > 0.f) ? e : 0.2f * e;                 // leaky_relu 0.2
        float newm = fmaxf(m, e);
        float corr = __expf(m - newm);                // first iter: exp(-inf)=0
        float p = __expf(e - newm);
        l = l * corr + p;
        const float* hrow = h + (size_t)s * (H * C) + lane * R;
        if constexpr (R >= 4) {
            const float4* hv = (const float4*)hrow;
#pragma unroll
            for (int q = 0; q < R / 4; q++) {
                float4 v = hv[q];
                acc[q * 4 + 0] = acc[q * 4 + 0] * corr + p * v.x;
                acc[q * 4 + 1] = acc[q * 4 + 1] * corr + p * v.y;
                acc[q * 4 + 2] = acc[q * 4 + 2] * corr + p * v.z;
                acc[q * 4 + 3] = acc[q * 4 + 3] * corr + p * v.w;
            }
        } else {
#pragma unroll
            for (int r = 0; r < R; r++) acc[r] = acc[r] * corr + p * hrow[r];
        }
        m = newm;
    }
    float inv = 1.f / l;
    float* orow = out + (size_t)n * (H * C) + lane * R;
#pragma unroll
    for (int r = 0; r < R; r++) {
        float v = acc[r] * inv + bias[lane * R + r];
        orow[r] = fmaxf(v, 0.f);                      // relu on every layer
    }
}

// ---------------------------------------------------------------------------

static inline size_t align_up(size_t x) { return (x + 255) & ~(size_t)255; }

extern "C" void kernel_launch(void* const* d_in, const int* in_sizes, int n_in,
                              void* d_out, int out_size, void* d_ws, size_t ws_size,
                              hipStream_t stream) {
    const float* x   = (const float*)d_in[0];
    const int*   ei  = (const int*)d_in[1];
    const float* W1  = (const float*)d_in[2];
    const float* a1s = (const float*)d_in[3];
    const float* a1d = (const float*)d_in[4];
    const float* b1  = (const float*)d_in[5];
    const float* W2  = (const float*)d_in[6];
    const float* a2s = (const float*)d_in[7];
    const float* a2d = (const float*)d_in[8];
    const float* b2  = (const float*)d_in[9];
    const float* W3  = (const float*)d_in[10];
    const float* a3s = (const float*)d_in[11];
    const float* a3d = (const float*)d_in[12];
    const float* b3  = (const float*)d_in[13];
    const float* W4  = (const float*)d_in[14];
    const float* a4s = (const float*)d_in[15];
    const float* a4d = (const float*)d_in[16];
    const float* b4  = (const float*)d_in[17];

    const int n  = in_sizes[0] / 256;    // 30000
    const int e0 = in_sizes[1] / 2;      // 480000
    const int et = e0 + n;               // +self loops

    // workspace layout
    char* w = (char*)d_ws;
    float* bufA = (float*)w;                 w += align_up((size_t)n * 512 * 4);
    float* bufB = (float*)w;                 w += align_up((size_t)n * 512 * 4);
    float* as_b = (float*)w;                 w += align_up((size_t)n * 4 * 4);
    float* ad_b = (float*)w;                 w += align_up((size_t)n * 4 * 4);
    int* row_ptr = (int*)w;                  w += align_up((size_t)(n + 1) * 4);
    int* counts  = (int*)w;                  w += align_up((size_t)n * 4);
    int* src_sorted = (int*)w;               w += align_up((size_t)et * 4);
    (void)ws_size;

    // ---- CSR build ----
    zero_int<<<(n + 255) / 256, 256, 0, stream>>>(counts, n);
    hist_kernel<<<(et + 255) / 256, 256, 0, stream>>>(ei, e0, n, counts);
    scan_kernel<<<1, 1024, 0, stream>>>(counts, row_ptr, n);
    zero_int<<<(n + 255) / 256, 256, 0, stream>>>(counts, n);
    scatter_kernel<<<(et + 255) / 256, 256, 0, stream>>>(ei, e0, n, row_ptr, counts, src_sorted);

    int nodeblocks = (n + 3) / 4;
    dim3 blk(256);

    // ---- Layer 1: 256 -> 4x128, concat ----
    {
        dim3 grid(512 / TN, (n + TM - 1) / TM);
        gemm_kernel<<<grid, blk, 0, stream>>>(x, W1, bufA, n, 256, 512);
        alpha_kernel<4, 128><<<nodeblocks, blk, 0, stream>>>(bufA, a1s, a1d, as_b, ad_b, n);
        agg_kernel<4, 128><<<nodeblocks, blk, 0, stream>>>(bufA, as_b, ad_b, row_ptr, src_sorted, b1, bufB, n);
    }
    // ---- Layer 2: 512 -> 4x128, concat ----
    {
        dim3 grid(512 / TN, (n + TM - 1) / TM);
        gemm_kernel<<<grid, blk, 0, stream>>>(bufB, W2, bufA, n, 512, 512);
        alpha_kernel<4, 128><<<nodeblocks, blk, 0, stream>>>(bufA, a2s, a2d, as_b, ad_b, n);
        agg_kernel<4, 128><<<nodeblocks, blk, 0, stream>>>(bufA, as_b, ad_b, row_ptr, src_sorted, b2, bufB, n);
    }
    // ---- Layer 3: 512 -> 4x64, concat ----
    {
        dim3 grid(256 / TN, (n + TM - 1) / TM);
        gemm_kernel<<<grid, blk, 0, stream>>>(bufB, W3, bufA, n, 512, 256);
        alpha_kernel<4, 64><<<nodeblocks, blk, 0, stream>>>(bufA, a3s, a3d, as_b, ad_b, n);
        agg_kernel<4, 64><<<nodeblocks, blk, 0, stream>>>(bufA, as_b, ad_b, row_ptr, src_sorted, b3, bufB, n);
    }
    // ---- Layer 4: 256 -> 1x64, mean(H=1) ----
    {
        dim3 grid(64 / TN, (n + TM - 1) / TM);
        gemm_kernel<<<grid, blk, 0, stream>>>(bufB, W4, bufA, n, 256, 64);
        alpha_kernel<1, 64><<<nodeblocks, blk, 0, stream>>>(bufA, a4s, a4d, as_b, ad_b, n);
        agg_kernel<1, 64><<<nodeblocks, blk, 0, stream>>>(bufA, as_b, ad_b, row_ptr, src_sorted, b4, (float*)d_out, n);
    }
}

// Round 2
// 864.269 us; speedup vs baseline: 1.2923x; 1.2923x over previous
//
#include <hip/hip_runtime.h>
#include <hip/hip_bf16.h>
#include <math.h>

// ---------------------------------------------------------------------------
// GAT 4-layer forward.
//   CSR build (hist -> scan -> scatter) once per call.
//   Per layer: split-bf16 MFMA GEMM (h = in @ W via A_hi*B_hi + A_lo*B_hi +
//   A_hi*B_lo, fp32-level accuracy at bf16 MFMA rate), alpha kernel, agg
//   kernel (online softmax gather) whose epilogue emits the NEXT layer's
//   bf16 hi/lo A' operand directly (layer 4 emits fp32 d_out).
// ---------------------------------------------------------------------------

typedef __attribute__((ext_vector_type(8))) __bf16 bf16x8;
typedef __attribute__((ext_vector_type(4))) float floatx4;

__device__ __forceinline__ unsigned short f2bf(float f) {   // RNE
    unsigned int u = __float_as_uint(f);
    u += 0x7fff + ((u >> 16) & 1);
    return (unsigned short)(u >> 16);
}
__device__ __forceinline__ float bf2f(unsigned short u) {
    return __uint_as_float(((unsigned int)u) << 16);
}

__device__ __forceinline__ void gload16(const void* g, void* l) {
    __builtin_amdgcn_global_load_lds(
        (const __attribute__((address_space(1))) void*)g,
        (__attribute__((address_space(3))) void*)l, 16, 0, 0);
}

// ---------------------------------------------------------------------------
// CSR build
// ---------------------------------------------------------------------------
static __global__ void zero_int(int* __restrict__ p, int n) {
    int i = blockIdx.x * blockDim.x + threadIdx.x;
    if (i < n) p[i] = 0;
}

static __global__ void hist_kernel(const int* __restrict__ ei, int e0, int n_nodes,
                                   int* __restrict__ counts) {
    int e = blockIdx.x * blockDim.x + threadIdx.x;
    int et = e0 + n_nodes;
    if (e >= et) return;
    int d = (e < e0) ? ei[e0 + e] : (e - e0);
    atomicAdd(&counts[d], 1);
}

static __global__ void scan_kernel(const int* __restrict__ counts,
                                   int* __restrict__ row_ptr, int n) {
    __shared__ int sdata[1024];
    __shared__ int carry;
    if (threadIdx.x == 0) carry = 0;
    __syncthreads();
    for (int base = 0; base < n; base += 1024) {
        int i = base + (int)threadIdx.x;
        int v = (i < n) ? counts[i] : 0;
        sdata[threadIdx.x] = v;
        __syncthreads();
        for (int off = 1; off < 1024; off <<= 1) {
            int t = 0;
            if ((int)threadIdx.x >= off) t = sdata[threadIdx.x - off];
            __syncthreads();
            if ((int)threadIdx.x >= off) sdata[threadIdx.x] += t;
            __syncthreads();
        }
        int inc = sdata[threadIdx.x] + carry;
        if (i < n) row_ptr[i + 1] = inc;
        __syncthreads();
        if (threadIdx.x == 1023) carry = inc;
        __syncthreads();
    }
    if (threadIdx.x == 0) row_ptr[0] = 0;
}

static __global__ void scatter_kernel(const int* __restrict__ ei, int e0, int n_nodes,
                                      const int* __restrict__ row_ptr,
                                      int* __restrict__ cursor,
                                      int* __restrict__ src_sorted) {
    int e = blockIdx.x * blockDim.x + threadIdx.x;
    int et = e0 + n_nodes;
    if (e >= et) return;
    int s, d;
    if (e < e0) { s = ei[e]; d = ei[e0 + e]; } else { s = e - e0; d = s; }
    int pos = atomicAdd(&cursor[d], 1);
    src_sorted[row_ptr[d] + pos] = s;
}

// ---------------------------------------------------------------------------
// hi/lo conversion kernels
// ---------------------------------------------------------------------------
// x[M,K] fp32 -> A'[M,2K] bf16 (cols 0..K-1 = hi, K..2K-1 = lo)
static __global__ void convA_kernel(const float* __restrict__ X,
                                    unsigned short* __restrict__ A, int M, int K) {
    int idx = blockIdx.x * 256 + threadIdx.x;
    if (idx >= M * K) return;
    int m = idx / K, k = idx % K;
    float v = X[idx];
    unsigned short hi = f2bf(v);
    size_t base = (size_t)m * (2 * K);
    A[base + k] = hi;
    A[base + K + k] = f2bf(v - bf2f(hi));
}

// W[K,N] fp32 -> BT'[Npad,3K] bf16 rows = W columns; [0:K)=hi [K:2K)=hi [2K:3K)=lo
static __global__ void convW_kernel(const float* __restrict__ W,
                                    unsigned short* __restrict__ BT,
                                    int K, int N, int Npad) {
    int idx = blockIdx.x * 256 + threadIdx.x;
    if (idx >= Npad * K) return;
    int n = idx / K, k = idx % K;
    float v = (n < N) ? W[(size_t)k * N + n] : 0.f;
    unsigned short hi = f2bf(v);
    unsigned short lo = f2bf(v - bf2f(hi));
    size_t base = (size_t)n * (3 * K);
    BT[base + k] = hi;
    BT[base + K + k] = hi;
    BT[base + 2 * K + k] = lo;
}

// ---------------------------------------------------------------------------
// split-bf16 MFMA GEMM: C[M,N] fp32 = A'[Mpad,2K] x B (via BT'[Npad,3K]).
// 128x128 tile, 256 thr (4 waves 2x2), BK=64, global_load_lds(16B) staging
// with XOR-chunk swizzle (16B chunks; LDS[row][ch] = G[row][ch ^ (row&7)]).
// Segments: (A hi, B hi), (A lo, B hi), (A hi, B lo).
// ---------------------------------------------------------------------------
#define BM 128
#define BN 128
#define BKK 64

__launch_bounds__(256)
static __global__ void gemm_mfma(const unsigned short* __restrict__ A,
                                 const unsigned short* __restrict__ B,
                                 float* __restrict__ C, int M, int K, int N) {
    __shared__ __align__(16) unsigned short lds[2 * BM * BKK];   // 16KB A + 16KB B
    const int tid  = threadIdx.x;
    const int lane = tid & 63;
    const int wave = tid >> 6;
    const int r0 = blockIdx.y * BM;
    const int c0 = blockIdx.x * BN;
    const int wm = (wave >> 1) * 64;
    const int wn = (wave & 1) * 64;
    const int q   = lane >> 4;
    const int m16 = lane & 15;

    floatx4 acc[4][4];
#pragma unroll
    for (int i = 0; i < 4; i++)
#pragma unroll
        for (int j = 0; j < 4; j++) acc[i][j] = {0.f, 0.f, 0.f, 0.f};

    const size_t sA = (size_t)(2 * K);
    const size_t sB = (size_t)(3 * K);
    char* ldsb = (char*)lds;

#pragma unroll 1
    for (int seg = 0; seg < 3; seg++) {
        const int aoff = (seg == 1) ? K : 0;
        const int boff = seg * K;
#pragma unroll 1
        for (int k0 = 0; k0 < K; k0 += BKK) {
            __syncthreads();
#pragma unroll
            for (int c = 0; c < 4; c++) {
                int slot = c * 256 + tid;
                int row = slot >> 3;          // 0..127
                int gc  = (slot & 7) ^ (row & 7);
                gload16(A + (size_t)(r0 + row) * sA + aoff + k0 + gc * 8,
                        ldsb + slot * 16);
                gload16(B + (size_t)(c0 + row) * sB + boff + k0 + gc * 8,
                        ldsb + 16384 + slot * 16);
            }
            __syncthreads();
#pragma unroll
            for (int ks = 0; ks < 2; ks++) {
                bf16x8 af[4], bfr[4];
#pragma unroll
                for (int i = 0; i < 4; i++) {
                    int row = wm + i * 16 + m16;
                    int ch  = (q + ks * 4) ^ (row & 7);
                    af[i] = *(const bf16x8*)(ldsb + (row * 8 + ch) * 16);
                }
#pragma unroll
                for (int j = 0; j < 4; j++) {
                    int row = wn + j * 16 + m16;
                    int ch  = (q + ks * 4) ^ (row & 7);
                    bfr[j] = *(const bf16x8*)(ldsb + 16384 + (row * 8 + ch) * 16);
                }
#pragma unroll
                for (int i = 0; i < 4; i++)
#pragma unroll
                    for (int j = 0; j < 4; j++)
                        acc[i][j] = __builtin_amdgcn_mfma_f32_16x16x32_bf16(
                            af[i], bfr[j], acc[i][j], 0, 0, 0);
            }
        }
    }
    // C/D layout: col = lane&15, row = (lane>>4)*4 + reg
#pragma unroll
    for (int i = 0; i < 4; i++)
#pragma unroll
        for (int j = 0; j < 4; j++)
#pragma unroll
            for (int r = 0; r < 4; r++) {
                int row = r0 + wm + i * 16 + q * 4 + r;
                int col = c0 + wn + j * 16 + m16;
                if (row < M && col < N) C[(size_t)row * N + col] = acc[i][j][r];
            }
}

// ---------------------------------------------------------------------------
// alpha kernel: as[n,h] = sum_c h[n,h,c]*a_src[h,c]; same for ad. One wave/node.
// ---------------------------------------------------------------------------
template <int H, int C>
__launch_bounds__(256)
static __global__ void alpha_kernel(const float* __restrict__ h,
                                    const float* __restrict__ a_src,
                                    const float* __restrict__ a_dst,
                                    float* __restrict__ as_out,
                                    float* __restrict__ ad_out, int n_nodes) {
    constexpr int R = H * C / 64;
    constexpr int G = 64 / H;
    int wave = threadIdx.x >> 6;
    int lane = threadIdx.x & 63;
    int n = blockIdx.x * 4 + wave;
    if (n >= n_nodes) return;
    const float* row = h + (size_t)n * (H * C) + lane * R;
    float ssrc = 0.f, sdst = 0.f;
#pragma unroll
    for (int r = 0; r < R; r++) {
        float v = row[r];
        int f = lane * R + r;
        ssrc += v * a_src[f];
        sdst += v * a_dst[f];
    }
#pragma unroll
    for (int off = G / 2; off > 0; off >>= 1) {
        ssrc += __shfl_down(ssrc, off);
        sdst += __shfl_down(sdst, off);
    }
    if ((lane & (G - 1)) == 0) {
        int head = lane / G;
        as_out[(size_t)n * H + head] = ssrc;
        ad_out[(size_t)n * H + head] = sdst;
    }
}

// ---------------------------------------------------------------------------
// aggregation: one wave/node, online softmax gather, fused bias+relu.
// BF16OUT: write next layer's A' operand (hi at [n,f], lo at [n,K+f], K=H*C);
// else write fp32 out.
// ---------------------------------------------------------------------------
template <int H, int C, bool BF16OUT>
__launch_bounds__(256)
static __global__ void agg_kernel(const float* __restrict__ h,
                                  const float* __restrict__ as_arr,
                                  const float* __restrict__ ad_arr,
                                  const int* __restrict__ row_ptr,
                                  const int* __restrict__ src_sorted,
                                  const float* __restrict__ bias,
                                  float* __restrict__ outf,
                                  unsigned short* __restrict__ outb, int n_nodes) {
    constexpr int R = H * C / 64;
    constexpr int G = 64 / H;
    constexpr int K = H * C;
    int wave = threadIdx.x >> 6;
    int lane = threadIdx.x & 63;
    int n = blockIdx.x * 4 + wave;
    if (n >= n_nodes) return;
    int myh = lane / G;
    float ad_n = ad_arr[(size_t)n * H + myh];
    int beg = row_ptr[n], end = row_ptr[n + 1];

    float m = -INFINITY, l = 0.f;
    float acc[R];
#pragma unroll
    for (int r = 0; r < R; r++) acc[r] = 0.f;

    for (int j = beg; j < end; j++) {
        int s = src_sorted[j];
        float e = as_arr[(size_t)s * H + myh] + ad_n;
        e = (e > 0.f) ? e : 0.2f * e;                 // leaky_relu 0.2
        float newm = fmaxf(m, e);
        float corr = __expf(m - newm);
        float p = __expf(e - newm);
        l = l * corr + p;
        const float* hrow = h + (size_t)s * K + lane * R;
        if constexpr (R >= 4) {
            const float4* hv = (const float4*)hrow;
#pragma unroll
            for (int qq = 0; qq < R / 4; qq++) {
                float4 v = hv[qq];
                acc[qq * 4 + 0] = acc[qq * 4 + 0] * corr + p * v.x;
                acc[qq * 4 + 1] = acc[qq * 4 + 1] * corr + p * v.y;
                acc[qq * 4 + 2] = acc[qq * 4 + 2] * corr + p * v.z;
                acc[qq * 4 + 3] = acc[qq * 4 + 3] * corr + p * v.w;
            }
        } else {
#pragma unroll
            for (int r = 0; r < R; r++) acc[r] = acc[r] * corr + p * hrow[r];
        }
        m = newm;
    }
    float inv = 1.f / l;
#pragma unroll
    for (int r = 0; r < R; r++) {
        float v = acc[r] * inv + bias[lane * R + r];
        v = fmaxf(v, 0.f);                            // relu (all 4 layers)
        if constexpr (BF16OUT) {
            unsigned short hi = f2bf(v);
            size_t base = (size_t)n * (2 * K) + lane * R + r;
            outb[base] = hi;
            outb[base + K] = f2bf(v - bf2f(hi));
        } else {
            outf[(size_t)n * K + lane * R + r] = v;
        }
    }
}

// ---------------------------------------------------------------------------

static inline size_t align_up(size_t x) { return (x + 255) & ~(size_t)255; }

extern "C" void kernel_launch(void* const* d_in, const int* in_sizes, int n_in,
                              void* d_out, int out_size, void* d_ws, size_t ws_size,
                              hipStream_t stream) {
    const float* x   = (const float*)d_in[0];
    const int*   ei  = (const int*)d_in[1];
    const float* W1  = (const float*)d_in[2];
    const float* a1s = (const float*)d_in[3];
    const float* a1d = (const float*)d_in[4];
    const float* b1  = (const float*)d_in[5];
    const float* W2  = (const float*)d_in[6];
    const float* a2s = (const float*)d_in[7];
    const float* a2d = (const float*)d_in[8];
    const float* b2  = (const float*)d_in[9];
    const float* W3  = (const float*)d_in[10];
    const float* a3s = (const float*)d_in[11];
    const float* a3d = (const float*)d_in[12];
    const float* b3  = (const float*)d_in[13];
    const float* W4  = (const float*)d_in[14];
    const float* a4s = (const float*)d_in[15];
    const float* a4d = (const float*)d_in[16];
    const float* b4  = (const float*)d_in[17];

    const int n  = in_sizes[0] / 256;    // 30000
    const int e0 = in_sizes[1] / 2;      // 480000
    const int et = e0 + n;
    const int Mpad = ((n + 127) / 128) * 128;   // 30080

    // workspace layout (~130 MB)
    char* w = (char*)d_ws;
    unsigned short* slotA = (unsigned short*)w;  w += align_up((size_t)Mpad * 1024 * 2);
    float* hbuf = (float*)w;                     w += align_up((size_t)n * 512 * 4);
    unsigned short* WT1 = (unsigned short*)w;    w += align_up((size_t)512 * 768 * 2);
    unsigned short* WT2 = (unsigned short*)w;    w += align_up((size_t)512 * 1536 * 2);
    unsigned short* WT3 = (unsigned short*)w;    w += align_up((size_t)256 * 1536 * 2);
    unsigned short* WT4 = (unsigned short*)w;    w += align_up((size_t)128 * 768 * 2);
    float* as_b = (float*)w;                     w += align_up((size_t)n * 4 * 4);
    float* ad_b = (float*)w;                     w += align_up((size_t)n * 4 * 4);
    int* row_ptr = (int*)w;                      w += align_up((size_t)(n + 1) * 4);
    int* counts  = (int*)w;                      w += align_up((size_t)n * 4);
    int* src_sorted = (int*)w;                   w += align_up((size_t)et * 4);
    (void)ws_size;

    dim3 blk(256);
    int nodeblocks = (n + 3) / 4;

    // ---- CSR build ----
    zero_int<<<(n + 255) / 256, 256, 0, stream>>>(counts, n);
    hist_kernel<<<(et + 255) / 256, 256, 0, stream>>>(ei, e0, n, counts);
    scan_kernel<<<1, 1024, 0, stream>>>(counts, row_ptr, n);
    zero_int<<<(n + 255) / 256, 256, 0, stream>>>(counts, n);
    scatter_kernel<<<(et + 255) / 256, 256, 0, stream>>>(ei, e0, n, row_ptr, counts, src_sorted);

    // ---- operand conversion ----
    convA_kernel<<<((n * 256) + 255) / 256, blk, 0, stream>>>(x, slotA, n, 256);
    convW_kernel<<<((512 * 256) + 255) / 256, blk, 0, stream>>>(W1, WT1, 256, 512, 512);
    convW_kernel<<<((512 * 512) + 255) / 256, blk, 0, stream>>>(W2, WT2, 512, 512, 512);
    convW_kernel<<<((256 * 512) + 255) / 256, blk, 0, stream>>>(W3, WT3, 512, 256, 256);
    convW_kernel<<<((128 * 256) + 255) / 256, blk, 0, stream>>>(W4, WT4, 256, 64, 128);

    const int mblocks = Mpad / 128;   // 235

    // ---- Layer 1: K=256 -> N=512 (4 heads x 128), concat ----
    gemm_mfma<<<dim3(4, mblocks), blk, 0, stream>>>(slotA, WT1, hbuf, n, 256, 512);
    alpha_kernel<4, 128><<<nodeblocks, blk, 0, stream>>>(hbuf, a1s, a1d, as_b, ad_b, n);
    agg_kernel<4, 128, true><<<nodeblocks, blk, 0, stream>>>(hbuf, as_b, ad_b, row_ptr, src_sorted, b1, nullptr, slotA, n);

    // ---- Layer 2: K=512 -> N=512 ----
    gemm_mfma<<<dim3(4, mblocks), blk, 0, stream>>>(slotA, WT2, hbuf, n, 512, 512);
    alpha_kernel<4, 128><<<nodeblocks, blk, 0, stream>>>(hbuf, a2s, a2d, as_b, ad_b, n);
    agg_kernel<4, 128, true><<<nodeblocks, blk, 0, stream>>>(hbuf, as_b, ad_b, row_ptr, src_sorted, b2, nullptr, slotA, n);

    // ---- Layer 3: K=512 -> N=256 (4 heads x 64), concat ----
    gemm_mfma<<<dim3(2, mblocks), blk, 0, stream>>>(slotA, WT3, hbuf, n, 512, 256);
    alpha_kernel<4, 64><<<nodeblocks, blk, 0, stream>>>(hbuf, a3s, a3d, as_b, ad_b, n);
    agg_kernel<4, 64, true><<<nodeblocks, blk, 0, stream>>>(hbuf, as_b, ad_b, row_ptr, src_sorted, b3, nullptr, slotA, n);

    // ---- Layer 4: K=256 -> N=64, 1 head, mean==identity ----
    gemm_mfma<<<dim3(1, mblocks), blk, 0, stream>>>(slotA, WT4, hbuf, n, 256, 64);
    alpha_kernel<1, 64><<<nodeblocks, blk, 0, stream>>>(hbuf, a4s, a4d, as_b, ad_b, n);
    agg_kernel<1, 64, false><<<nodeblocks, blk, 0, stream>>>(hbuf, as_b, ad_b, row_ptr, src_sorted, b4, (float*)d_out, nullptr, n);
}